// Round 5
// baseline (577.284 us; speedup 1.0000x reference)
//
#include <hip/hip_runtime.h>
#include <hip/hip_bf16.h>

typedef float f32x4 __attribute__((ext_vector_type(4)));
typedef __bf16 bf16x8v __attribute__((ext_vector_type(8)));
typedef __bf16 bf16x4v __attribute__((ext_vector_type(4)));
typedef unsigned uint2v __attribute__((ext_vector_type(2)));
typedef bf16x8v __attribute__((may_alias)) bf16x8;
typedef bf16x4v __attribute__((may_alias)) bf16x4;
typedef uint2v __attribute__((may_alias)) u32x2;

typedef __attribute__((address_space(1))) const void gvoid_t;
typedef __attribute__((address_space(3))) void lvoid_t;

#define DEVINL __device__ __forceinline__

#define BDIM 2
#define TDIM 2048
#define CDIM 2048
#define NHEAD 16
#define DHEAD 128
#define MROWS 4096
#define WSZ ((size_t)CDIM * CDIM)
#define XSZ ((size_t)MROWS * CDIM)

// barrier without the compiler's conservative vmcnt(0) drain: LDS ops are
// flushed (lgkmcnt), in-flight global prefetch loads stay in flight.
#define BARRIER_LGKM() asm volatile("s_waitcnt lgkmcnt(0)\ns_barrier" ::: "memory")

DEVINL __bf16 f2bf(float f) {
  unsigned u = __builtin_bit_cast(unsigned, f);
  u += 0x7fffu + ((u >> 16) & 1u);  // RNE
  unsigned short h = (unsigned short)(u >> 16);
  return __builtin_bit_cast(__bf16, h);
}

// pack two f32 -> two bf16 (truncation) in one v_perm
DEVINL unsigned pk2bf_trunc(float lo, float hi) {
  return __builtin_amdgcn_perm(__builtin_bit_cast(unsigned, hi),
                               __builtin_bit_cast(unsigned, lo), 0x07060302);
}

DEVINL void gl2lds16(const void* g, void* l) {
  __builtin_amdgcn_global_load_lds((gvoid_t*)g, (lvoid_t*)l, 16, 0, 0);
}

// ---------------------------------------------------------------------------
// dtype probe (bf16 vs f32) + zero the attn work-stealing counter.
__global__ void detect_dtype(const unsigned* __restrict__ w,
                             int* __restrict__ flag, int* __restrict__ cnt) {
  const int l = threadIdx.x;  // 64 threads
  if (l == 0) *cnt = 0;
  const unsigned word = w[l];
  const unsigned e = (word >> 7) & 0xFFu;
  const int vote = (e >= 0x70u && e <= 0x87u) ? 1 : 0;
  const unsigned long long m = __ballot(vote);
  if (l == 0) *flag = (__popcll(m) >= 32) ? 1 : 0;
}

// ---------------------------------------------------------------------------
__global__ __launch_bounds__(256) void cvt_src(const void* __restrict__ in,
                                               __bf16* __restrict__ out,
                                               const int* __restrict__ flag,
                                               int n8) {
  const int i = blockIdx.x * 256 + threadIdx.x;
  if (i >= n8) return;
  if (*flag) {
    ((bf16x8*)out)[i] = ((const bf16x8*)in)[i];
  } else {
    const float* f = (const float*)in + (size_t)i * 8;
    bf16x8v v;
#pragma unroll
    for (int j = 0; j < 8; ++j) v[j] = f2bf(f[j]);
    ((bf16x8*)out)[i] = v;
  }
}

// ---------------------------------------------------------------------------
__global__ __launch_bounds__(256) void cvt_wt(
    const void* __restrict__ w0, const void* __restrict__ w1,
    const void* __restrict__ w2, const void* __restrict__ w3,
    __bf16* __restrict__ out, const int* __restrict__ flag) {
  __shared__ __attribute__((aligned(16))) __bf16 tile[64][68];
  const void* W = (blockIdx.z == 0) ? w0 : (blockIdx.z == 1) ? w1
                : (blockIdx.z == 2) ? w2 : w3;
  __bf16* Wt = out + (size_t)blockIdx.z * WSZ;
  const int tx = threadIdx.x & 63, ty = threadIdx.x >> 6;
  const int k0 = blockIdx.x * 64, n0 = blockIdx.y * 64;
  const int fl = *flag;
#pragma unroll
  for (int i = ty; i < 64; i += 4) {
    const size_t off = (size_t)(k0 + i) * CDIM + n0 + tx;
    const float v = fl ? (float)((const __bf16*)W)[off] : ((const float*)W)[off];
    tile[i][tx] = f2bf(v);
  }
  __syncthreads();
#pragma unroll
  for (int i = ty; i < 64; i += 4)
    Wt[(size_t)(n0 + i) * CDIM + k0 + tx] = tile[tx][i];
}

// ---------------------------------------------------------------------------
__global__ __launch_bounds__(256) void cvt_bias(
    const void* __restrict__ b0, const void* __restrict__ b1,
    const void* __restrict__ b2, const void* __restrict__ b3,
    float* __restrict__ out, const int* __restrict__ flag) {
  const int i = blockIdx.x * 256 + threadIdx.x;  // 0..8191
  const void* b = (i < 2048) ? b0 : (i < 4096) ? b1 : (i < 6144) ? b2 : b3;
  const int idx = i & 2047;
  out[i] = (*flag) ? (float)((const __bf16*)b)[idx] : ((const float*)b)[idx];
}

// ---------------------------------------------------------------------------
// Fused QKV GEMM: C[4096][6144] = src @ [Wq|Wk|Wv]t^T + bias.
// Q,K -> [b,h,t,d]; V -> [b,h,d,s] (transposed, bf16x4 vector stores).
__global__ __launch_bounds__(256, 3) void gemm_qkv(
    const __bf16* __restrict__ A, const __bf16* __restrict__ Bt,
    const float* __restrict__ bias, __bf16* __restrict__ qb,
    __bf16* __restrict__ kb, __bf16* __restrict__ vtb) {
  constexpr int K = CDIM;
  __shared__ __attribute__((aligned(16))) __bf16 Als[128 * 32];
  __shared__ __attribute__((aligned(16))) __bf16 Bls[128 * 32];
  const int tid = threadIdx.x;
  const int w = tid >> 6, l = tid & 63;
  const int quad = l >> 4, l16 = l & 15;
  const int wm = (w >> 1) * 64, wn = (w & 1) * 64;
  const int m0 = blockIdx.x * 128, n0 = blockIdx.y * 128;  // n0 in [0,6144)

  f32x4 acc[4][4];
#pragma unroll
  for (int i = 0; i < 4; ++i)
#pragma unroll
    for (int j = 0; j < 4; ++j) acc[i][j] = (f32x4){0.f, 0.f, 0.f, 0.f};

  const int srow = w * 32 + (l >> 2);
  const int swz = (l & 3) ^ ((l >> 3) & 3);
  const __bf16* ga = A + (size_t)(m0 + srow) * K + swz * 8;
  const __bf16* gb = Bt + (size_t)(n0 + srow) * K + swz * 8;
  __bf16* la = Als + w * 1024;
  __bf16* lb = Bls + w * 1024;
  const int cswz = (quad ^ ((l16 >> 1) & 3)) * 8;

  for (int k0 = 0; k0 < K; k0 += 32) {
    __syncthreads();
#pragma unroll
    for (int j = 0; j < 2; ++j) {
      gl2lds16(ga + (size_t)j * 16 * K + k0, la + j * 512);
      gl2lds16(gb + (size_t)j * 16 * K + k0, lb + j * 512);
    }
    __syncthreads();
    bf16x8 af[4], bfr[4];
#pragma unroll
    for (int i = 0; i < 4; ++i)
      af[i] = *(const bf16x8*)&Als[(wm + i * 16 + l16) * 32 + cswz];
#pragma unroll
    for (int j = 0; j < 4; ++j)
      bfr[j] = *(const bf16x8*)&Bls[(wn + j * 16 + l16) * 32 + cswz];
#pragma unroll
    for (int i = 0; i < 4; ++i)
#pragma unroll
      for (int j = 0; j < 4; ++j)
        acc[i][j] = __builtin_amdgcn_mfma_f32_16x16x32_bf16(af[i], bfr[j],
                                                            acc[i][j], 0, 0, 0);
  }

  const int mat = n0 >> 11;  // 0=Q 1=K 2=V (uniform per block)
#pragma unroll
  for (int j = 0; j < 4; ++j) {
    const int n = n0 + wn + j * 16 + l16;  // global column 0..6143
    const int nn = n & 2047;
    const int h = nn >> 7, d = nn & 127;
    const float bv = bias[n];
#pragma unroll
    for (int i = 0; i < 4; ++i) {
      const int mbase = m0 + wm + i * 16 + quad * 4;
      const int bb = mbase >> 11, t = mbase & 2047;
      if (mat == 2) {
        bf16x4v v4;
#pragma unroll
        for (int r = 0; r < 4; ++r) v4[r] = f2bf(acc[i][j][r] + bv);
        *(bf16x4*)&vtb[((size_t)(bb * NHEAD + h) * DHEAD + d) * TDIM + t] = v4;
      } else {
        __bf16* outp = (mat == 0) ? qb : kb;
#pragma unroll
        for (int r = 0; r < 4; ++r)
          outp[((size_t)(bb * NHEAD + h) * TDIM + t + r) * DHEAD + d] =
              f2bf(acc[i][j][r] + bv);
      }
    }
  }
}

// ---------------------------------------------------------------------------
// Output GEMM: d_out = ctx @ Wo^T + bo (f32 or bf16 out per flag).
__global__ __launch_bounds__(256, 3) void gemm_out(
    const __bf16* __restrict__ A, const __bf16* __restrict__ Bt,
    const float* __restrict__ bias, void* __restrict__ outp,
    const int* __restrict__ flag) {
  constexpr int K = CDIM;
  __shared__ __attribute__((aligned(16))) __bf16 Als[128 * 32];
  __shared__ __attribute__((aligned(16))) __bf16 Bls[128 * 32];
  const int tid = threadIdx.x;
  const int w = tid >> 6, l = tid & 63;
  const int quad = l >> 4, l16 = l & 15;
  const int wm = (w >> 1) * 64, wn = (w & 1) * 64;
  const int m0 = blockIdx.x * 128, n0 = blockIdx.y * 128;
  const int ofl = *flag;

  f32x4 acc[4][4];
#pragma unroll
  for (int i = 0; i < 4; ++i)
#pragma unroll
    for (int j = 0; j < 4; ++j) acc[i][j] = (f32x4){0.f, 0.f, 0.f, 0.f};

  const int srow = w * 32 + (l >> 2);
  const int swz = (l & 3) ^ ((l >> 3) & 3);
  const __bf16* ga = A + (size_t)(m0 + srow) * K + swz * 8;
  const __bf16* gb = Bt + (size_t)(n0 + srow) * K + swz * 8;
  __bf16* la = Als + w * 1024;
  __bf16* lb = Bls + w * 1024;
  const int cswz = (quad ^ ((l16 >> 1) & 3)) * 8;

  for (int k0 = 0; k0 < K; k0 += 32) {
    __syncthreads();
#pragma unroll
    for (int j = 0; j < 2; ++j) {
      gl2lds16(ga + (size_t)j * 16 * K + k0, la + j * 512);
      gl2lds16(gb + (size_t)j * 16 * K + k0, lb + j * 512);
    }
    __syncthreads();
    bf16x8 af[4], bfr[4];
#pragma unroll
    for (int i = 0; i < 4; ++i)
      af[i] = *(const bf16x8*)&Als[(wm + i * 16 + l16) * 32 + cswz];
#pragma unroll
    for (int j = 0; j < 4; ++j)
      bfr[j] = *(const bf16x8*)&Bls[(wn + j * 16 + l16) * 32 + cswz];
#pragma unroll
    for (int i = 0; i < 4; ++i)
#pragma unroll
      for (int j = 0; j < 4; ++j)
        acc[i][j] = __builtin_amdgcn_mfma_f32_16x16x32_bf16(af[i], bfr[j],
                                                            acc[i][j], 0, 0, 0);
  }

#pragma unroll
  for (int j = 0; j < 4; ++j) {
    const int n = n0 + wn + j * 16 + l16;
    const float bv = bias[n];
#pragma unroll
    for (int i = 0; i < 4; ++i) {
#pragma unroll
      for (int r = 0; r < 4; ++r) {
        const int m = m0 + wm + i * 16 + quad * 4 + r;
        const float v = acc[i][j][r] + bv;
        if (ofl) ((__bf16*)outp)[(size_t)m * CDIM + n] = f2bf(v);
        else     ((float*)outp)[(size_t)m * CDIM + n] = v;
      }
    }
  }
}

// ---------------------------------------------------------------------------
// Flash-style causal attention (R3 structure): persistent blocks +
// work-stealing, LDS-staged K/V, 2 lgkm-only barriers per s-block,
// register-double-buffered staging. 3 blocks/CU (48.5 KB LDS, VGPR<=168).
__global__ __launch_bounds__(256, 3) void attn(
    const __bf16* __restrict__ Q, const __bf16* __restrict__ K,
    const __bf16* __restrict__ Vt, __bf16* __restrict__ ctx,
    int* __restrict__ cnt) {
  constexpr float CSC = 0.12753139726f;  // log2(e)/sqrt(128)
  __shared__ __attribute__((aligned(16))) __bf16 Kls[64 * 128];   // [s][d]
  __shared__ __attribute__((aligned(16))) __bf16 Vls[128 * 64];   // [d][s]
  __shared__ __attribute__((aligned(16))) __bf16 Pls[4][32 * 64]; // [t][s]
  __shared__ int jobLds;

  const int tid = threadIdx.x;
  const int w = tid >> 6, l = tid & 63, quad = l >> 4, l16 = l & 15;

  const int krow = tid >> 4;                 // 0..15, +16 per pass
  const int kcol = tid & 15;
  const int kldsoff = ((kcol ^ krow) * 8);
  const int vrow = tid >> 3;                 // 0..31, +32 per pass
  const int vcol = tid & 7;
  const int vldsoff = ((vcol ^ (vrow & 7)) * 8);

  for (;;) {
    __syncthreads();
    if (tid == 0) jobLds = atomicAdd(cnt, 1);
    __syncthreads();
    const int j = jobLds;
    if (j >= 512) break;
    const int qt = 15 - (j >> 5);   // all qt=15 jobs first (LPT)
    const int bh = j & 31;
    const int t0w = qt * 128 + w * 32;
    const __bf16* Qbh = Q + (size_t)bh * TDIM * DHEAD;
    const __bf16* Kbh = K + (size_t)bh * TDIM * DHEAD;
    const __bf16* Vbh = Vt + (size_t)bh * TDIM * DHEAD;

    bf16x8 qf[2][4];
#pragma unroll
    for (int tt = 0; tt < 2; ++tt)
#pragma unroll
      for (int ks = 0; ks < 4; ++ks)
        qf[tt][ks] = *(const bf16x8*)(Qbh +
                     (size_t)(t0w + tt * 16 + l16) * DHEAD + ks * 32 + quad * 8);

    f32x4 oacc[8][2];
#pragma unroll
    for (int dt = 0; dt < 8; ++dt)
#pragma unroll
      for (int tt = 0; tt < 2; ++tt) oacc[dt][tt] = (f32x4){0.f, 0.f, 0.f, 0.f};
    float mrow[2] = {-1e30f, -1e30f};
    float lrow[2] = {0.f, 0.f};

    const int nsb = 2 * (qt + 1);

    // prefetch s-block 0 into regs
    bf16x8 kr[4], vr[4];
#pragma unroll
    for (int p = 0; p < 4; ++p)
      kr[p] = *(const bf16x8*)(Kbh + (size_t)(p * 16 + krow) * DHEAD + kcol * 8);
#pragma unroll
    for (int p = 0; p < 4; ++p)
      vr[p] = *(const bf16x8*)(Vbh + (size_t)(p * 32 + vrow) * TDIM + vcol * 8);

    for (int sb = 0; sb < nsb; ++sb) {
      const int s0 = sb * 64;
      BARRIER_LGKM();  // prior iteration's LDS reads complete
#pragma unroll
      for (int p = 0; p < 4; ++p)
        *(bf16x8*)&Kls[(p * 16 + krow) * 128 + kldsoff] = kr[p];
#pragma unroll
      for (int p = 0; p < 4; ++p)
        *(bf16x8*)&Vls[(p * 32 + vrow) * 64 + vldsoff] = vr[p];
      if (sb + 1 < nsb) {
        const int s1 = s0 + 64;
#pragma unroll
        for (int p = 0; p < 4; ++p)
          kr[p] = *(const bf16x8*)(Kbh + (size_t)(s1 + p * 16 + krow) * DHEAD +
                                   kcol * 8);
#pragma unroll
        for (int p = 0; p < 4; ++p)
          vr[p] = *(const bf16x8*)(Vbh + (size_t)(p * 32 + vrow) * TDIM + s1 +
                                   vcol * 8);
      }
      BARRIER_LGKM();  // staging visible; prefetch loads remain in flight
      if (s0 > t0w + 31) continue;  // fully masked for this wave

      // S^T = K.Q^T : D[row=s: quad*4+r][col=t: l16]
      f32x4 sacc[4][2];
#pragma unroll
      for (int st = 0; st < 4; ++st)
#pragma unroll
        for (int tt = 0; tt < 2; ++tt) sacc[st][tt] = (f32x4){0.f, 0.f, 0.f, 0.f};
#pragma unroll
      for (int ks = 0; ks < 4; ++ks) {
        bf16x8 kf[4];
#pragma unroll
        for (int st = 0; st < 4; ++st)
          kf[st] = *(const bf16x8*)&Kls[(st * 16 + l16) * 128 +
                                        (((ks * 4 + quad) ^ l16) * 8)];
#pragma unroll
        for (int st = 0; st < 4; ++st)
#pragma unroll
          for (int tt = 0; tt < 2; ++tt)
            sacc[st][tt] = __builtin_amdgcn_mfma_f32_16x16x32_bf16(
                kf[st], qf[tt][ks], sacc[st][tt], 0, 0, 0);
      }
      if (s0 + 63 > t0w) {  // causal mask near diagonal
#pragma unroll
        for (int st = 0; st < 4; ++st)
#pragma unroll
          for (int tt = 0; tt < 2; ++tt)
#pragma unroll
            for (int r = 0; r < 4; ++r) {
              const int s = s0 + st * 16 + quad * 4 + r;
              const int t = t0w + tt * 16 + l16;
              if (s > t) sacc[st][tt][r] = -1e30f;
            }
      }
      // online softmax per t-column
#pragma unroll
      for (int tt = 0; tt < 2; ++tt) {
        float vm = -1e30f;
#pragma unroll
        for (int st = 0; st < 4; ++st)
#pragma unroll
          for (int r = 0; r < 4; ++r) vm = fmaxf(vm, sacc[st][tt][r]);
        vm = fmaxf(vm, __shfl_xor(vm, 16));
        vm = fmaxf(vm, __shfl_xor(vm, 32));
        const float mnew = fmaxf(mrow[tt], vm);
        // skip the 64-mul rescale when no lane's max grew
        if (__ballot(mnew > mrow[tt])) {
          const float alpha = exp2f((mrow[tt] - mnew) * CSC);
          lrow[tt] *= alpha;
#pragma unroll
          for (int dt = 0; dt < 8; ++dt)
#pragma unroll
            for (int r = 0; r < 4; ++r) oacc[dt][tt][r] *= alpha;
          mrow[tt] = mnew;
        }
        float rs = 0.f;
#pragma unroll
        for (int st = 0; st < 4; ++st) {
          const float p0 = exp2f((sacc[st][tt][0] - mnew) * CSC);
          const float p1 = exp2f((sacc[st][tt][1] - mnew) * CSC);
          const float p2 = exp2f((sacc[st][tt][2] - mnew) * CSC);
          const float p3 = exp2f((sacc[st][tt][3] - mnew) * CSC);
          rs += (p0 + p1) + (p2 + p3);
          u32x2 pk = {pk2bf_trunc(p0, p1), pk2bf_trunc(p2, p3)};
          *(u32x2*)&Pls[w][(tt * 16 + l16) * 64 +
                           (((st * 2 + (quad >> 1)) ^ (l16 & 7)) * 8) +
                           (quad & 1) * 4] = pk;
        }
        rs += __shfl_xor(rs, 16);
        rs += __shfl_xor(rs, 32);
        lrow[tt] += rs;
      }
      // intra-wave P write->read ordering (wave-private region, no barrier)
      asm volatile("s_waitcnt lgkmcnt(0)" ::: "memory");
      // O^T += V^T.P^T : D[row=d][col=t]
#pragma unroll
      for (int ks = 0; ks < 2; ++ks) {
        bf16x8 pf[2];
#pragma unroll
        for (int tt = 0; tt < 2; ++tt)
          pf[tt] = *(const bf16x8*)&Pls[w][(tt * 16 + l16) * 64 +
                                           (((ks * 4 + quad) ^ (l16 & 7)) * 8)];
#pragma unroll
        for (int dt = 0; dt < 8; ++dt) {
          const bf16x8 vf =
              *(const bf16x8*)&Vls[(dt * 16 + l16) * 64 +
                                   (((ks * 4 + quad) ^ (l16 & 7)) * 8)];
#pragma unroll
          for (int tt = 0; tt < 2; ++tt)
            oacc[dt][tt] = __builtin_amdgcn_mfma_f32_16x16x32_bf16(
                vf, pf[tt], oacc[dt][tt], 0, 0, 0);
        }
      }
    }

    // epilogue: O^T[d][t]/l -> ctx[b][t][h*128+d], bf16x4 stores
    const int b = bh >> 4, h = bh & 15;
#pragma unroll
    for (int tt = 0; tt < 2; ++tt) {
      const float rinv = 1.0f / lrow[tt];
      const int t = t0w + tt * 16 + l16;
      __bf16* cp = ctx + ((size_t)(b * TDIM + t)) * CDIM + h * DHEAD;
#pragma unroll
      for (int dt = 0; dt < 8; ++dt) {
        bf16x4v v4;
#pragma unroll
        for (int r = 0; r < 4; ++r) v4[r] = f2bf(oacc[dt][tt][r] * rinv);
        *(bf16x4*)&cp[dt * 16 + quad * 4] = v4;
      }
    }
  }
}

// ---------------------------------------------------------------------------
extern "C" void kernel_launch(void* const* d_in, const int* in_sizes, int n_in,
                              void* d_out, int out_size, void* d_ws,
                              size_t ws_size, hipStream_t stream) {
  const void* src = d_in[0];
  const void* Wq = d_in[1];
  const void* bq = d_in[2];
  const void* Wk = d_in[3];
  const void* bk = d_in[4];
  const void* Wv = d_in[5];
  const void* bv = d_in[6];
  const void* Wo = d_in[7];
  const void* bo = d_in[8];

  char* wsb = (char*)d_ws;
  int* flag = (int*)wsb;                  // +0
  int* cnt = (int*)(wsb + 128);           // +128 (work-steal counter)
  __bf16* srcbf = (__bf16*)(wsb + 256);
  __bf16* wqt = srcbf + XSZ;              // q,k,v,o transposed, contiguous
  __bf16* wkt = wqt + WSZ;
  __bf16* wvt = wkt + WSZ;
  __bf16* wot = wvt + WSZ;
  __bf16* qb = wot + WSZ;                 // [B*NH][T][D]
  __bf16* kb = qb + XSZ;                  // [B*NH][T][D]
  __bf16* vtb = kb + XSZ;                 // [B*NH][D][T]
  float* biasf = (float*)(vtb + XSZ);     // 4 x 2048 f32
  __bf16* ctx = srcbf;                    // reuse (src consumed by then)

  detect_dtype<<<1, 64, 0, stream>>>((const unsigned*)src, flag, cnt);
  cvt_src<<<4096, 256, 0, stream>>>(src, srcbf, flag, (int)(XSZ / 8));
  cvt_wt<<<dim3(32, 32, 4), 256, 0, stream>>>(Wq, Wk, Wv, Wo, wqt, flag);
  cvt_bias<<<32, 256, 0, stream>>>(bq, bk, bv, bo, biasf, flag);
  gemm_qkv<<<dim3(32, 48), 256, 0, stream>>>(srcbf, wqt, biasf, qb, kb, vtb);
  attn<<<768, 256, 0, stream>>>(qb, kb, vtb, ctx, cnt);
  gemm_out<<<dim3(32, 16), 256, 0, stream>>>(ctx, wot, biasf + 6144, d_out, flag);
}

// Round 6
// 427.952 us; speedup vs baseline: 1.3489x; 1.3489x over previous
//
#include <hip/hip_runtime.h>
#include <hip/hip_bf16.h>

typedef float f32x4 __attribute__((ext_vector_type(4)));
typedef __bf16 bf16x8v __attribute__((ext_vector_type(8)));
typedef __bf16 bf16x4v __attribute__((ext_vector_type(4)));
typedef unsigned uint2v __attribute__((ext_vector_type(2)));
typedef bf16x8v __attribute__((may_alias)) bf16x8;
typedef bf16x4v __attribute__((may_alias)) bf16x4;
typedef uint2v __attribute__((may_alias)) u32x2;

typedef __attribute__((address_space(1))) const void gvoid_t;
typedef __attribute__((address_space(3))) void lvoid_t;

#define DEVINL __device__ __forceinline__

#define BDIM 2
#define TDIM 2048
#define CDIM 2048
#define NHEAD 16
#define DHEAD 128
#define MROWS 4096
#define WSZ ((size_t)CDIM * CDIM)
#define XSZ ((size_t)MROWS * CDIM)

// barrier without the compiler's conservative vmcnt(0) drain: LDS ops are
// flushed (lgkmcnt), in-flight global prefetch loads stay in flight.
#define BARRIER_LGKM() asm volatile("s_waitcnt lgkmcnt(0)\ns_barrier" ::: "memory")

DEVINL __bf16 f2bf(float f) {
  unsigned u = __builtin_bit_cast(unsigned, f);
  u += 0x7fffu + ((u >> 16) & 1u);  // RNE
  unsigned short h = (unsigned short)(u >> 16);
  return __builtin_bit_cast(__bf16, h);
}

// pack two f32 -> two bf16 (truncation) in one v_perm
DEVINL unsigned pk2bf_trunc(float lo, float hi) {
  return __builtin_amdgcn_perm(__builtin_bit_cast(unsigned, hi),
                               __builtin_bit_cast(unsigned, lo), 0x07060302);
}

DEVINL void gl2lds16(const void* g, void* l) {
  __builtin_amdgcn_global_load_lds((gvoid_t*)g, (lvoid_t*)l, 16, 0, 0);
}

// ---------------------------------------------------------------------------
// dtype probe (bf16 vs f32) + zero the attn work-stealing counter.
__global__ void detect_dtype(const unsigned* __restrict__ w,
                             int* __restrict__ flag, int* __restrict__ cnt) {
  const int l = threadIdx.x;  // 64 threads
  if (l == 0) *cnt = 0;
  const unsigned word = w[l];
  const unsigned e = (word >> 7) & 0xFFu;
  const int vote = (e >= 0x70u && e <= 0x87u) ? 1 : 0;
  const unsigned long long m = __ballot(vote);
  if (l == 0) *flag = (__popcll(m) >= 32) ? 1 : 0;
}

// ---------------------------------------------------------------------------
__global__ __launch_bounds__(256) void cvt_src(const void* __restrict__ in,
                                               __bf16* __restrict__ out,
                                               const int* __restrict__ flag,
                                               int n8) {
  const int i = blockIdx.x * 256 + threadIdx.x;
  if (i >= n8) return;
  if (*flag) {
    ((bf16x8*)out)[i] = ((const bf16x8*)in)[i];
  } else {
    const float* f = (const float*)in + (size_t)i * 8;
    bf16x8v v;
#pragma unroll
    for (int j = 0; j < 8; ++j) v[j] = f2bf(f[j]);
    ((bf16x8*)out)[i] = v;
  }
}

// ---------------------------------------------------------------------------
__global__ __launch_bounds__(256) void cvt_wt(
    const void* __restrict__ w0, const void* __restrict__ w1,
    const void* __restrict__ w2, const void* __restrict__ w3,
    __bf16* __restrict__ out, const int* __restrict__ flag) {
  __shared__ __attribute__((aligned(16))) __bf16 tile[64][68];
  const void* W = (blockIdx.z == 0) ? w0 : (blockIdx.z == 1) ? w1
                : (blockIdx.z == 2) ? w2 : w3;
  __bf16* Wt = out + (size_t)blockIdx.z * WSZ;
  const int tx = threadIdx.x & 63, ty = threadIdx.x >> 6;
  const int k0 = blockIdx.x * 64, n0 = blockIdx.y * 64;
  const int fl = *flag;
#pragma unroll
  for (int i = ty; i < 64; i += 4) {
    const size_t off = (size_t)(k0 + i) * CDIM + n0 + tx;
    const float v = fl ? (float)((const __bf16*)W)[off] : ((const float*)W)[off];
    tile[i][tx] = f2bf(v);
  }
  __syncthreads();
#pragma unroll
  for (int i = ty; i < 64; i += 4)
    Wt[(size_t)(n0 + i) * CDIM + k0 + tx] = tile[tx][i];
}

// ---------------------------------------------------------------------------
__global__ __launch_bounds__(256) void cvt_bias(
    const void* __restrict__ b0, const void* __restrict__ b1,
    const void* __restrict__ b2, const void* __restrict__ b3,
    float* __restrict__ out, const int* __restrict__ flag) {
  const int i = blockIdx.x * 256 + threadIdx.x;  // 0..8191
  const void* b = (i < 2048) ? b0 : (i < 4096) ? b1 : (i < 6144) ? b2 : b3;
  const int idx = i & 2047;
  out[i] = (*flag) ? (float)((const __bf16*)b)[idx] : ((const float*)b)[idx];
}

// ---------------------------------------------------------------------------
// Fused QKV GEMM: C[4096][6144] = src @ [Wq|Wk|Wv]t^T + bias.
// Q,K -> [b,h,t,d]; V -> [b,h,d,s] (transposed, bf16x4 vector stores).
// NOTE: no min-waves launch_bounds arg — m97-class kernels need ~228 regs
// (164 VGPR + 64 AGPR); forcing 3 waves/EU caps the budget and spills
// (R5 evidence: VGPR 84 + 228 MB scratch writes on attn).
__global__ __launch_bounds__(256) void gemm_qkv(
    const __bf16* __restrict__ A, const __bf16* __restrict__ Bt,
    const float* __restrict__ bias, __bf16* __restrict__ qb,
    __bf16* __restrict__ kb, __bf16* __restrict__ vtb) {
  constexpr int K = CDIM;
  __shared__ __attribute__((aligned(16))) __bf16 Als[128 * 32];
  __shared__ __attribute__((aligned(16))) __bf16 Bls[128 * 32];
  const int tid = threadIdx.x;
  const int w = tid >> 6, l = tid & 63;
  const int quad = l >> 4, l16 = l & 15;
  const int wm = (w >> 1) * 64, wn = (w & 1) * 64;
  const int m0 = blockIdx.x * 128, n0 = blockIdx.y * 128;  // n0 in [0,6144)

  f32x4 acc[4][4];
#pragma unroll
  for (int i = 0; i < 4; ++i)
#pragma unroll
    for (int j = 0; j < 4; ++j) acc[i][j] = (f32x4){0.f, 0.f, 0.f, 0.f};

  const int srow = w * 32 + (l >> 2);
  const int swz = (l & 3) ^ ((l >> 3) & 3);
  const __bf16* ga = A + (size_t)(m0 + srow) * K + swz * 8;
  const __bf16* gb = Bt + (size_t)(n0 + srow) * K + swz * 8;
  __bf16* la = Als + w * 1024;
  __bf16* lb = Bls + w * 1024;
  const int cswz = (quad ^ ((l16 >> 1) & 3)) * 8;

  for (int k0 = 0; k0 < K; k0 += 32) {
    __syncthreads();
#pragma unroll
    for (int j = 0; j < 2; ++j) {
      gl2lds16(ga + (size_t)j * 16 * K + k0, la + j * 512);
      gl2lds16(gb + (size_t)j * 16 * K + k0, lb + j * 512);
    }
    __syncthreads();
    bf16x8 af[4], bfr[4];
#pragma unroll
    for (int i = 0; i < 4; ++i)
      af[i] = *(const bf16x8*)&Als[(wm + i * 16 + l16) * 32 + cswz];
#pragma unroll
    for (int j = 0; j < 4; ++j)
      bfr[j] = *(const bf16x8*)&Bls[(wn + j * 16 + l16) * 32 + cswz];
#pragma unroll
    for (int i = 0; i < 4; ++i)
#pragma unroll
      for (int j = 0; j < 4; ++j)
        acc[i][j] = __builtin_amdgcn_mfma_f32_16x16x32_bf16(af[i], bfr[j],
                                                            acc[i][j], 0, 0, 0);
  }

  const int mat = n0 >> 11;  // 0=Q 1=K 2=V (uniform per block)
#pragma unroll
  for (int j = 0; j < 4; ++j) {
    const int n = n0 + wn + j * 16 + l16;  // global column 0..6143
    const int nn = n & 2047;
    const int h = nn >> 7, d = nn & 127;
    const float bv = bias[n];
#pragma unroll
    for (int i = 0; i < 4; ++i) {
      const int mbase = m0 + wm + i * 16 + quad * 4;
      const int bb = mbase >> 11, t = mbase & 2047;
      if (mat == 2) {
        bf16x4v v4;
#pragma unroll
        for (int r = 0; r < 4; ++r) v4[r] = f2bf(acc[i][j][r] + bv);
        *(bf16x4*)&vtb[((size_t)(bb * NHEAD + h) * DHEAD + d) * TDIM + t] = v4;
      } else {
        __bf16* outp = (mat == 0) ? qb : kb;
#pragma unroll
        for (int r = 0; r < 4; ++r)
          outp[((size_t)(bb * NHEAD + h) * TDIM + t + r) * DHEAD + d] =
              f2bf(acc[i][j][r] + bv);
      }
    }
  }
}

// ---------------------------------------------------------------------------
// Output GEMM: d_out = ctx @ Wo^T + bo (f32 or bf16 out per flag).
__global__ __launch_bounds__(256) void gemm_out(
    const __bf16* __restrict__ A, const __bf16* __restrict__ Bt,
    const float* __restrict__ bias, void* __restrict__ outp,
    const int* __restrict__ flag) {
  constexpr int K = CDIM;
  __shared__ __attribute__((aligned(16))) __bf16 Als[128 * 32];
  __shared__ __attribute__((aligned(16))) __bf16 Bls[128 * 32];
  const int tid = threadIdx.x;
  const int w = tid >> 6, l = tid & 63;
  const int quad = l >> 4, l16 = l & 15;
  const int wm = (w >> 1) * 64, wn = (w & 1) * 64;
  const int m0 = blockIdx.x * 128, n0 = blockIdx.y * 128;
  const int ofl = *flag;

  f32x4 acc[4][4];
#pragma unroll
  for (int i = 0; i < 4; ++i)
#pragma unroll
    for (int j = 0; j < 4; ++j) acc[i][j] = (f32x4){0.f, 0.f, 0.f, 0.f};

  const int srow = w * 32 + (l >> 2);
  const int swz = (l & 3) ^ ((l >> 3) & 3);
  const __bf16* ga = A + (size_t)(m0 + srow) * K + swz * 8;
  const __bf16* gb = Bt + (size_t)(n0 + srow) * K + swz * 8;
  __bf16* la = Als + w * 1024;
  __bf16* lb = Bls + w * 1024;
  const int cswz = (quad ^ ((l16 >> 1) & 3)) * 8;

  for (int k0 = 0; k0 < K; k0 += 32) {
    __syncthreads();
#pragma unroll
    for (int j = 0; j < 2; ++j) {
      gl2lds16(ga + (size_t)j * 16 * K + k0, la + j * 512);
      gl2lds16(gb + (size_t)j * 16 * K + k0, lb + j * 512);
    }
    __syncthreads();
    bf16x8 af[4], bfr[4];
#pragma unroll
    for (int i = 0; i < 4; ++i)
      af[i] = *(const bf16x8*)&Als[(wm + i * 16 + l16) * 32 + cswz];
#pragma unroll
    for (int j = 0; j < 4; ++j)
      bfr[j] = *(const bf16x8*)&Bls[(wn + j * 16 + l16) * 32 + cswz];
#pragma unroll
    for (int i = 0; i < 4; ++i)
#pragma unroll
      for (int j = 0; j < 4; ++j)
        acc[i][j] = __builtin_amdgcn_mfma_f32_16x16x32_bf16(af[i], bfr[j],
                                                            acc[i][j], 0, 0, 0);
  }

#pragma unroll
  for (int j = 0; j < 4; ++j) {
    const int n = n0 + wn + j * 16 + l16;
    const float bv = bias[n];
#pragma unroll
    for (int i = 0; i < 4; ++i) {
#pragma unroll
      for (int r = 0; r < 4; ++r) {
        const int m = m0 + wm + i * 16 + quad * 4 + r;
        const float v = acc[i][j][r] + bv;
        if (ofl) ((__bf16*)outp)[(size_t)m * CDIM + n] = f2bf(v);
        else     ((float*)outp)[(size_t)m * CDIM + n] = v;
      }
    }
  }
}

// ---------------------------------------------------------------------------
// Flash-style causal attention (R3 structure, proven 124 us): persistent
// blocks + work-stealing, LDS-staged K/V, 2 lgkm-only barriers per s-block,
// register-double-buffered staging. (256,2): kernel needs ~180 regs/wave —
// forcing 3 waves/EU spills to scratch (R5: 228 MB writes, 3x slower).
__global__ __launch_bounds__(256, 2) void attn(
    const __bf16* __restrict__ Q, const __bf16* __restrict__ K,
    const __bf16* __restrict__ Vt, __bf16* __restrict__ ctx,
    int* __restrict__ cnt) {
  constexpr float CSC = 0.12753139726f;  // log2(e)/sqrt(128)
  __shared__ __attribute__((aligned(16))) __bf16 Kls[64 * 128];   // [s][d]
  __shared__ __attribute__((aligned(16))) __bf16 Vls[128 * 64];   // [d][s]
  __shared__ __attribute__((aligned(16))) __bf16 Pls[4][32 * 64]; // [t][s]
  __shared__ int jobLds;

  const int tid = threadIdx.x;
  const int w = tid >> 6, l = tid & 63, quad = l >> 4, l16 = l & 15;

  const int krow = tid >> 4;                 // 0..15, +16 per pass
  const int kcol = tid & 15;
  const int kldsoff = ((kcol ^ krow) * 8);
  const int vrow = tid >> 3;                 // 0..31, +32 per pass
  const int vcol = tid & 7;
  const int vldsoff = ((vcol ^ (vrow & 7)) * 8);

  for (;;) {
    __syncthreads();
    if (tid == 0) jobLds = atomicAdd(cnt, 1);
    __syncthreads();
    const int j = jobLds;
    if (j >= 512) break;
    const int qt = 15 - (j >> 5);   // all qt=15 jobs first (LPT)
    const int bh = j & 31;
    const int t0w = qt * 128 + w * 32;
    const __bf16* Qbh = Q + (size_t)bh * TDIM * DHEAD;
    const __bf16* Kbh = K + (size_t)bh * TDIM * DHEAD;
    const __bf16* Vbh = Vt + (size_t)bh * TDIM * DHEAD;

    bf16x8 qf[2][4];
#pragma unroll
    for (int tt = 0; tt < 2; ++tt)
#pragma unroll
      for (int ks = 0; ks < 4; ++ks)
        qf[tt][ks] = *(const bf16x8*)(Qbh +
                     (size_t)(t0w + tt * 16 + l16) * DHEAD + ks * 32 + quad * 8);

    f32x4 oacc[8][2];
#pragma unroll
    for (int dt = 0; dt < 8; ++dt)
#pragma unroll
      for (int tt = 0; tt < 2; ++tt) oacc[dt][tt] = (f32x4){0.f, 0.f, 0.f, 0.f};
    float mrow[2] = {-1e30f, -1e30f};
    float lrow[2] = {0.f, 0.f};

    const int nsb = 2 * (qt + 1);

    // prefetch s-block 0 into regs
    bf16x8 kr[4], vr[4];
#pragma unroll
    for (int p = 0; p < 4; ++p)
      kr[p] = *(const bf16x8*)(Kbh + (size_t)(p * 16 + krow) * DHEAD + kcol * 8);
#pragma unroll
    for (int p = 0; p < 4; ++p)
      vr[p] = *(const bf16x8*)(Vbh + (size_t)(p * 32 + vrow) * TDIM + vcol * 8);

    for (int sb = 0; sb < nsb; ++sb) {
      const int s0 = sb * 64;
      BARRIER_LGKM();  // prior iteration's LDS reads complete
#pragma unroll
      for (int p = 0; p < 4; ++p)
        *(bf16x8*)&Kls[(p * 16 + krow) * 128 + kldsoff] = kr[p];
#pragma unroll
      for (int p = 0; p < 4; ++p)
        *(bf16x8*)&Vls[(p * 32 + vrow) * 64 + vldsoff] = vr[p];
      if (sb + 1 < nsb) {
        const int s1 = s0 + 64;
#pragma unroll
        for (int p = 0; p < 4; ++p)
          kr[p] = *(const bf16x8*)(Kbh + (size_t)(s1 + p * 16 + krow) * DHEAD +
                                   kcol * 8);
#pragma unroll
        for (int p = 0; p < 4; ++p)
          vr[p] = *(const bf16x8*)(Vbh + (size_t)(p * 32 + vrow) * TDIM + s1 +
                                   vcol * 8);
      }
      BARRIER_LGKM();  // staging visible; prefetch loads remain in flight
      if (s0 > t0w + 31) continue;  // fully masked for this wave

      // S^T = K.Q^T : D[row=s: quad*4+r][col=t: l16]
      f32x4 sacc[4][2];
#pragma unroll
      for (int st = 0; st < 4; ++st)
#pragma unroll
        for (int tt = 0; tt < 2; ++tt) sacc[st][tt] = (f32x4){0.f, 0.f, 0.f, 0.f};
#pragma unroll
      for (int ks = 0; ks < 4; ++ks) {
        bf16x8 kf[4];
#pragma unroll
        for (int st = 0; st < 4; ++st)
          kf[st] = *(const bf16x8*)&Kls[(st * 16 + l16) * 128 +
                                        (((ks * 4 + quad) ^ l16) * 8)];
#pragma unroll
        for (int st = 0; st < 4; ++st)
#pragma unroll
          for (int tt = 0; tt < 2; ++tt)
            sacc[st][tt] = __builtin_amdgcn_mfma_f32_16x16x32_bf16(
                kf[st], qf[tt][ks], sacc[st][tt], 0, 0, 0);
      }
      if (s0 + 63 > t0w) {  // causal mask near diagonal
#pragma unroll
        for (int st = 0; st < 4; ++st)
#pragma unroll
          for (int tt = 0; tt < 2; ++tt)
#pragma unroll
            for (int r = 0; r < 4; ++r) {
              const int s = s0 + st * 16 + quad * 4 + r;
              const int t = t0w + tt * 16 + l16;
              if (s > t) sacc[st][tt][r] = -1e30f;
            }
      }
      // online softmax per t-column
#pragma unroll
      for (int tt = 0; tt < 2; ++tt) {
        float vm = -1e30f;
#pragma unroll
        for (int st = 0; st < 4; ++st)
#pragma unroll
          for (int r = 0; r < 4; ++r) vm = fmaxf(vm, sacc[st][tt][r]);
        vm = fmaxf(vm, __shfl_xor(vm, 16));
        vm = fmaxf(vm, __shfl_xor(vm, 32));
        const float mnew = fmaxf(mrow[tt], vm);
        // skip the 64-mul rescale when no lane's max grew
        if (__ballot(mnew > mrow[tt])) {
          const float alpha = exp2f((mrow[tt] - mnew) * CSC);
          lrow[tt] *= alpha;
#pragma unroll
          for (int dt = 0; dt < 8; ++dt)
#pragma unroll
            for (int r = 0; r < 4; ++r) oacc[dt][tt][r] *= alpha;
          mrow[tt] = mnew;
        }
        float rs = 0.f;
#pragma unroll
        for (int st = 0; st < 4; ++st) {
          const float p0 = exp2f((sacc[st][tt][0] - mnew) * CSC);
          const float p1 = exp2f((sacc[st][tt][1] - mnew) * CSC);
          const float p2 = exp2f((sacc[st][tt][2] - mnew) * CSC);
          const float p3 = exp2f((sacc[st][tt][3] - mnew) * CSC);
          rs += (p0 + p1) + (p2 + p3);
          u32x2 pk = {pk2bf_trunc(p0, p1), pk2bf_trunc(p2, p3)};
          *(u32x2*)&Pls[w][(tt * 16 + l16) * 64 +
                           (((st * 2 + (quad >> 1)) ^ (l16 & 7)) * 8) +
                           (quad & 1) * 4] = pk;
        }
        rs += __shfl_xor(rs, 16);
        rs += __shfl_xor(rs, 32);
        lrow[tt] += rs;
      }
      // intra-wave P write->read ordering (wave-private region, no barrier)
      asm volatile("s_waitcnt lgkmcnt(0)" ::: "memory");
      // O^T += V^T.P^T : D[row=d][col=t]
#pragma unroll
      for (int ks = 0; ks < 2; ++ks) {
        bf16x8 pf[2];
#pragma unroll
        for (int tt = 0; tt < 2; ++tt)
          pf[tt] = *(const bf16x8*)&Pls[w][(tt * 16 + l16) * 64 +
                                           (((ks * 4 + quad) ^ (l16 & 7)) * 8)];
#pragma unroll
        for (int dt = 0; dt < 8; ++dt) {
          const bf16x8 vf =
              *(const bf16x8*)&Vls[(dt * 16 + l16) * 64 +
                                   (((ks * 4 + quad) ^ (l16 & 7)) * 8)];
#pragma unroll
          for (int tt = 0; tt < 2; ++tt)
            oacc[dt][tt] = __builtin_amdgcn_mfma_f32_16x16x32_bf16(
                vf, pf[tt], oacc[dt][tt], 0, 0, 0);
        }
      }
    }

    // epilogue: O^T[d][t]/l -> ctx[b][t][h*128+d], bf16x4 stores
    const int b = bh >> 4, h = bh & 15;
#pragma unroll
    for (int tt = 0; tt < 2; ++tt) {
      const float rinv = 1.0f / lrow[tt];
      const int t = t0w + tt * 16 + l16;
      __bf16* cp = ctx + ((size_t)(b * TDIM + t)) * CDIM + h * DHEAD;
#pragma unroll
      for (int dt = 0; dt < 8; ++dt) {
        bf16x4v v4;
#pragma unroll
        for (int r = 0; r < 4; ++r) v4[r] = f2bf(oacc[dt][tt][r] * rinv);
        *(bf16x4*)&cp[dt * 16 + quad * 4] = v4;
      }
    }
  }
}

// ---------------------------------------------------------------------------
extern "C" void kernel_launch(void* const* d_in, const int* in_sizes, int n_in,
                              void* d_out, int out_size, void* d_ws,
                              size_t ws_size, hipStream_t stream) {
  const void* src = d_in[0];
  const void* Wq = d_in[1];
  const void* bq = d_in[2];
  const void* Wk = d_in[3];
  const void* bk = d_in[4];
  const void* Wv = d_in[5];
  const void* bv = d_in[6];
  const void* Wo = d_in[7];
  const void* bo = d_in[8];

  char* wsb = (char*)d_ws;
  int* flag = (int*)wsb;                  // +0
  int* cnt = (int*)(wsb + 128);           // +128 (work-steal counter)
  __bf16* srcbf = (__bf16*)(wsb + 256);
  __bf16* wqt = srcbf + XSZ;              // q,k,v,o transposed, contiguous
  __bf16* wkt = wqt + WSZ;
  __bf16* wvt = wkt + WSZ;
  __bf16* wot = wvt + WSZ;
  __bf16* qb = wot + WSZ;                 // [B*NH][T][D]
  __bf16* kb = qb + XSZ;                  // [B*NH][T][D]
  __bf16* vtb = kb + XSZ;                 // [B*NH][D][T]
  float* biasf = (float*)(vtb + XSZ);     // 4 x 2048 f32
  __bf16* ctx = srcbf;                    // reuse (src consumed by then)

  detect_dtype<<<1, 64, 0, stream>>>((const unsigned*)src, flag, cnt);
  cvt_src<<<4096, 256, 0, stream>>>(src, srcbf, flag, (int)(XSZ / 8));
  cvt_wt<<<dim3(32, 32, 4), 256, 0, stream>>>(Wq, Wk, Wv, Wo, wqt, flag);
  cvt_bias<<<32, 256, 0, stream>>>(bq, bk, bv, bo, biasf, flag);
  gemm_qkv<<<dim3(32, 48), 256, 0, stream>>>(srcbf, wqt, biasf, qb, kb, vtb);
  attn<<<512, 256, 0, stream>>>(qb, kb, vtb, ctx, cnt);
  gemm_out<<<dim3(32, 16), 256, 0, stream>>>(ctx, wot, biasf + 6144, d_out, flag);
}